// Round 1
// baseline (773.493 us; speedup 1.0000x reference)
//
#include <hip/hip_runtime.h>
#include <cmath>

#define TSIZE (1 << 19)   // hash table entries per level

typedef __bf16 bf16x8 __attribute__((ext_vector_type(8)));
typedef float  f32x4  __attribute__((ext_vector_type(4)));

struct Res16 { int r[16]; };

// float -> bf16 bits, round-to-nearest-even
static __device__ __forceinline__ short f2bf(float f) {
    union { float f; unsigned u; } v; v.f = f;
    unsigned r = v.u + 0x7FFFu + ((v.u >> 16) & 1u);
    return (short)(r >> 16);
}

// softplus(100 v)/100, stable form: (max(t,0) + log1p(exp(-|t|)))/100
static __device__ __forceinline__ float sp100(float v) {
    float t = 100.0f * v;
    float e = __expf(-fabsf(t));
    return 0.01f * (fmaxf(t, 0.0f) + __logf(1.0f + e));
}

// swizzled LDS offset: row m, col k, row stride `stride` (shorts).
// k-blocks of 8 XORed with (m&7) -> conflict-free ds_read_b128 A-frag loads.
static __device__ __forceinline__ int swz(int m, int k, int stride) {
    return m * stride + ((((k >> 3) ^ (m & 7)) << 3) | (k & 7));
}

// Pack W0 [256,121] and W1 [256,256] (row-major [out,in]) into MFMA B-fragment
// order: element ((kt*256 + n)*4 + q)*8 + j  holds  W[n][kt*32 + q*8 + j] (bf16).
// Lane (n = lane&15 slice, q = lane>>4) then loads 8 contiguous bf16 = 16 B.
__global__ __launch_bounds__(256) void pack_weights(
    const float* __restrict__ W0, const float* __restrict__ W1,
    short* __restrict__ B0p, short* __restrict__ B1p) {
    int i = blockIdx.x * 256 + threadIdx.x;      // 0..65535
    int j = i & 7, q = (i >> 3) & 3, n = (i >> 5) & 255, kt = i >> 13;
    int k = kt * 32 + q * 8 + j;
    if (i < 32768) {                             // B0p: kt 0..3 (K=128, 121 used)
        B0p[i] = f2bf(k < 121 ? W0[n * 121 + k] : 0.0f);
    }
    B1p[i] = f2bf(W1[n * 256 + k]);              // B1p: kt 0..7 (K=256)
}

__global__ __launch_bounds__(256) void fused_mlp(
    const float* __restrict__ x, const float* __restrict__ table,
    const float* __restrict__ b0, const float* __restrict__ b1,
    const float* __restrict__ W2, const float* __restrict__ b2,
    const short* __restrict__ B0p, const short* __restrict__ B1p,
    float* __restrict__ out, int npts, Res16 R)
{
    __shared__ short sA[64 * 128];   // input tile  [64 pts][K=128] bf16, swizzled (16 KB)
    __shared__ short sB[64 * 256];   // hidden0     [64 pts][K=256] bf16, swizzled (32 KB)
    __shared__ float sP[64 * 4];     // layer-2 partial dots [row][wave] (1 KB)

    const int tid = threadIdx.x;
    const int blk = blockIdx.x;

    // ---------------- Phase E: encode 64 points into sA ----------------------
    {
        const int m = tid >> 2;          // local point 0..63
        const int g = tid & 3;           // 4 workers per point
        int pt = blk * 64 + m;
        if (pt > npts - 1) pt = npts - 1;
        float xv[3];
        xv[0] = x[pt * 3 + 0];
        xv[1] = x[pt * 3 + 1];
        xv[2] = x[pt * 3 + 2];

        if (g == 0) {                    // raw coords, cols 0..2
            #pragma unroll
            for (int d = 0; d < 3; ++d) sA[swz(m, d, 128)] = f2bf(xv[d]);
        }
        if (g == 1) {                    // zero pad cols 121..127
            #pragma unroll
            for (int k = 121; k < 128; ++k) sA[swz(m, k, 128)] = 0;
        }
        // positional embed: sin cols 3+3f+d, cos cols 30+3f+d, freqs f = g, g+4, g+8
        for (int f = g; f < 9; f += 4) {
            float fs = (float)(1 << f);
            #pragma unroll
            for (int d = 0; d < 3; ++d) {
                float v = xv[d] * fs;
                sA[swz(m, 3 + f * 3 + d, 128)]  = f2bf(__builtin_sinf(v));
                sA[swz(m, 30 + f * 3 + d, 128)] = f2bf(__builtin_cosf(v));
            }
        }
        // hash-grid levels g*4 .. g*4+3 -> cols 57 + 4*lvl
        #pragma unroll
        for (int li = 0; li < 4; ++li) {
            int i0 = R.r[li], i1 = R.r[4 + li], i2 = R.r[8 + li], i3 = R.r[12 + li];
            int res = (g == 0) ? i0 : (g == 1) ? i1 : (g == 2) ? i2 : i3;
            int lvl = g * 4 + li;
            int rp1 = res + 1;
            bool dense = (rp1 <= 80);    // (res+1)^3 <= 2^19  <=>  res+1 <= 80
            float fx[3]; int pi[3];
            #pragma unroll
            for (int d = 0; d < 3; ++d) {
                float p  = xv[d] * (float)res;
                float pf = floorf(p);
                fx[d] = p - pf;
                int q = (int)pf;
                pi[d] = min(max(q, 0), res - 1);
            }
            float a0 = 0.f, a1 = 0.f, a2 = 0.f, a3 = 0.f;
            const float* tb = table + (size_t)lvl * (TSIZE * 4);
            #pragma unroll
            for (int c = 0; c < 8; ++c) {
                int cx = pi[0] + (c & 1);
                int cy = pi[1] + ((c >> 1) & 1);
                int cz = pi[2] + ((c >> 2) & 1);
                unsigned di = (unsigned)(cx + cy * rp1 + cz * rp1 * rp1);
                unsigned hi = ((unsigned)cx ^ ((unsigned)cy * 2654435761u)
                                            ^ ((unsigned)cz * 805459861u)) & (unsigned)(TSIZE - 1);
                unsigned idx = dense ? di : hi;
                float4 t = *(const float4*)(tb + (size_t)idx * 4);
                float w = ((c & 1) ? fx[0] : 1.0f - fx[0])
                        * ((c & 2) ? fx[1] : 1.0f - fx[1])
                        * ((c & 4) ? fx[2] : 1.0f - fx[2]);
                a0 += w * t.x; a1 += w * t.y; a2 += w * t.z; a3 += w * t.w;
            }
            int kb = 57 + lvl * 4;
            sA[swz(m, kb + 0, 128)] = f2bf(a0);
            sA[swz(m, kb + 1, 128)] = f2bf(a1);
            sA[swz(m, kb + 2, 128)] = f2bf(a2);
            sA[swz(m, kb + 3, 128)] = f2bf(a3);
        }
    }

    // ---------------- MFMA MLP ----------------------------------------------
    const int lane = tid & 63, w = tid >> 6;       // wave w covers cols w*64..w*64+63
    const int quad = lane >> 4, l15 = lane & 15;
    const int nb = w * 64;

    float b0r[4], b1r[4], w2r[4];
    #pragma unroll
    for (int ni = 0; ni < 4; ++ni) {
        int col = nb + ni * 16 + l15;
        b0r[ni] = b0[col]; b1r[ni] = b1[col]; w2r[ni] = W2[col];
    }

    __syncthreads();   // sA ready

    const f32x4 zero = {0.f, 0.f, 0.f, 0.f};
    f32x4 acc[4][4];
    #pragma unroll
    for (int mi = 0; mi < 4; ++mi)
        #pragma unroll
        for (int ni = 0; ni < 4; ++ni) acc[mi][ni] = zero;

    // GEMM0: [64 x 121(pad 128)] @ W0^T -> softplus -> sB
    #pragma unroll
    for (int kt = 0; kt < 4; ++kt) {
        bf16x8 a[4], bfr[4];
        #pragma unroll
        for (int mi = 0; mi < 4; ++mi) {
            int mm = mi * 16 + l15;
            int blkk = kt * 4 + quad;
            a[mi] = *(const bf16x8*)&sA[mm * 128 + ((blkk ^ (mm & 7)) << 3)];
        }
        #pragma unroll
        for (int ni = 0; ni < 4; ++ni)
            bfr[ni] = *(const bf16x8*)&B0p[((kt * 256 + nb + ni * 16 + l15) * 4 + quad) * 8];
        #pragma unroll
        for (int mi = 0; mi < 4; ++mi)
            #pragma unroll
            for (int ni = 0; ni < 4; ++ni)
                acc[mi][ni] = __builtin_amdgcn_mfma_f32_16x16x32_bf16(a[mi], bfr[ni], acc[mi][ni], 0, 0, 0);
    }

    // epilogue0: bias + softplus -> bf16 sB (swizzled). C frag: col=lane&15, row=quad*4+r
    #pragma unroll
    for (int mi = 0; mi < 4; ++mi)
        #pragma unroll
        for (int ni = 0; ni < 4; ++ni)
            #pragma unroll
            for (int r = 0; r < 4; ++r) {
                int row = mi * 16 + quad * 4 + r;
                int col = nb + ni * 16 + l15;
                sB[swz(row, col, 256)] = f2bf(sp100(acc[mi][ni][r] + b0r[ni]));
            }

    __syncthreads();   // sB (H0) ready

    #pragma unroll
    for (int mi = 0; mi < 4; ++mi)
        #pragma unroll
        for (int ni = 0; ni < 4; ++ni) acc[mi][ni] = zero;

    // GEMM1: [64 x 256] @ W1^T
    #pragma unroll
    for (int kt = 0; kt < 8; ++kt) {
        bf16x8 a[4], bfr[4];
        #pragma unroll
        for (int mi = 0; mi < 4; ++mi) {
            int mm = mi * 16 + l15;
            int blkk = kt * 4 + quad;
            a[mi] = *(const bf16x8*)&sB[mm * 256 + ((blkk ^ (mm & 7)) << 3)];
        }
        #pragma unroll
        for (int ni = 0; ni < 4; ++ni)
            bfr[ni] = *(const bf16x8*)&B1p[((kt * 256 + nb + ni * 16 + l15) * 4 + quad) * 8];
        #pragma unroll
        for (int mi = 0; mi < 4; ++mi)
            #pragma unroll
            for (int ni = 0; ni < 4; ++ni)
                acc[mi][ni] = __builtin_amdgcn_mfma_f32_16x16x32_bf16(a[mi], bfr[ni], acc[mi][ni], 0, 0, 0);
    }

    // epilogue1 fused with layer 2: out = softplus(H0@W1^T + b1) . W2 + b2
    #pragma unroll
    for (int mi = 0; mi < 4; ++mi)
        #pragma unroll
        for (int r = 0; r < 4; ++r) {
            float p = 0.0f;
            #pragma unroll
            for (int ni = 0; ni < 4; ++ni)
                p += sp100(acc[mi][ni][r] + b1r[ni]) * w2r[ni];
            // reduce across the 16 lanes of this quad (they hold the 16 cols)
            p += __shfl_xor(p, 1);
            p += __shfl_xor(p, 2);
            p += __shfl_xor(p, 4);
            p += __shfl_xor(p, 8);
            if (l15 == 0) sP[(mi * 16 + quad * 4 + r) * 4 + w] = p;
        }

    __syncthreads();

    if (tid < 64) {
        float s = sP[tid * 4 + 0] + sP[tid * 4 + 1] + sP[tid * 4 + 2] + sP[tid * 4 + 3] + b2[0];
        int pt = blk * 64 + tid;
        if (pt < npts) out[pt] = s;
    }
}

extern "C" void kernel_launch(void* const* d_in, const int* in_sizes, int n_in,
                              void* d_out, int out_size, void* d_ws, size_t ws_size,
                              hipStream_t stream) {
    const float* x     = (const float*)d_in[0];
    const float* table = (const float*)d_in[1];
    const float* W0    = (const float*)d_in[2];
    const float* b0    = (const float*)d_in[3];
    const float* W1    = (const float*)d_in[4];
    const float* b1    = (const float*)d_in[5];
    const float* W2    = (const float*)d_in[6];
    const float* b2    = (const float*)d_in[7];
    float* out = (float*)d_out;
    int npts = in_sizes[0] / 3;

    // ws layout: B0p 32768 bf16 (64 KB) | B1p 65536 bf16 (128 KB)
    short* B0p = (short*)d_ws;
    short* B1p = B0p + 32768;

    // RES table: must match Python bit-for-bit -> identical libm expression.
    Res16 R;
    double s = ::pow(2.0, ::log2(2048.0 / 16.0) / 15.0);
    for (int l = 0; l < 16; ++l) R.r[l] = (int)::ceil(16.0 * ::pow(s, (double)l));

    hipLaunchKernelGGL(pack_weights, dim3(256), dim3(256), 0, stream, W0, W1, B0p, B1p);
    int nblk = (npts + 63) / 64;
    hipLaunchKernelGGL(fused_mlp, dim3(nblk), dim3(256), 0, stream,
                       x, table, b0, b1, W2, b2, B0p, B1p, out, npts, R);
}

// Round 2
// 496.032 us; speedup vs baseline: 1.5594x; 1.5594x over previous
//
#include <hip/hip_runtime.h>
#include <cmath>

#define TSIZE (1 << 19)   // hash table entries per level

typedef __bf16 bf16x8 __attribute__((ext_vector_type(8)));
typedef float  f32x4  __attribute__((ext_vector_type(4)));

struct Res16 { int r[16]; };

// float -> bf16 bits, round-to-nearest-even
static __device__ __forceinline__ short f2bf(float f) {
    union { float f; unsigned u; } v; v.f = f;
    unsigned r = v.u + 0x7FFFu + ((v.u >> 16) & 1u);
    return (short)(r >> 16);
}

// softplus(100 v)/100, stable form: (max(t,0) + log1p(exp(-|t|)))/100
static __device__ __forceinline__ float sp100(float v) {
    float t = 100.0f * v;
    float e = __expf(-fabsf(t));
    return 0.01f * (fmaxf(t, 0.0f) + __logf(1.0f + e));
}

// swizzled LDS offset: row m, col k, row stride `stride` (shorts).
// k-blocks of 8 XORed with (m&7) -> conflict-free ds_read_b128 A-frag loads.
static __device__ __forceinline__ int swz(int m, int k, int stride) {
    return m * stride + ((((k >> 3) ^ (m & 7)) << 3) | (k & 7));
}

static __device__ __forceinline__ bool bit(const unsigned mk[4], int k) {
    return (mk[k >> 5] >> (k & 31)) & 1u;
}

// Pack W0 [256,121] and W1 [256,256] (row-major [out,in]) into MFMA B-fragment
// order: element ((kt*256 + n)*4 + q)*8 + j  holds  W[n][kt*32 + q*8 + j] (bf16).
// Also: block 0 scans W0 for live (any-nonzero) input columns -> mask[4] bitmask.
// Dead columns (zero weight column) need no encode work in fused_mlp: with this
// problem's geometric init only cols 0..2 are live, so the whole hash-gather +
// sin/cos phase is provably dead weight and gets skipped data-driven.
__global__ __launch_bounds__(256) void pack_weights(
    const float* __restrict__ W0, const float* __restrict__ W1,
    short* __restrict__ B0p, short* __restrict__ B1p, unsigned* __restrict__ mask) {
    __shared__ unsigned char lv[128];
    int tid = threadIdx.x;
    int i = blockIdx.x * 256 + tid;              // 0..65535
    int j = i & 7, q = (i >> 3) & 3, n = (i >> 5) & 255, kt = i >> 13;
    int k = kt * 32 + q * 8 + j;
    if (i < 32768) {                             // B0p: kt 0..3 (K=128, 121 used)
        B0p[i] = f2bf(k < 121 ? W0[n * 121 + k] : 0.0f);
    }
    B1p[i] = f2bf(W1[n * 256 + k]);              // B1p: kt 0..7 (K=256)

    if (blockIdx.x == 0) {
        if (tid < 128) {
            unsigned char v = 0;
            if (tid < 121) {
                for (int r = 0; r < 256; ++r)
                    if (W0[r * 121 + tid] != 0.0f) { v = 1; break; }
            }
            lv[tid] = v;
        }
        __syncthreads();
        if (tid < 4) {
            unsigned w = 0;
            for (int b = 0; b < 32; ++b) if (lv[tid * 32 + b]) w |= (1u << b);
            mask[tid] = w;
        }
    }
}

__global__ __launch_bounds__(256) void fused_mlp(
    const float* __restrict__ x, const float* __restrict__ table,
    const float* __restrict__ b0, const float* __restrict__ b1,
    const float* __restrict__ W2, const float* __restrict__ b2,
    const short* __restrict__ B0p, const short* __restrict__ B1p,
    const unsigned* __restrict__ mask,
    float* __restrict__ out, int npts, Res16 R)
{
    __shared__ short sA[64 * 128];   // input tile  [64 pts][K=128] bf16, swizzled (16 KB)
    __shared__ short sB[64 * 256];   // hidden0     [64 pts][K=256] bf16, swizzled (32 KB)
    __shared__ float sP[64 * 4];     // layer-2 partial dots [row][wave] (1 KB)

    const int tid = threadIdx.x;
    const int blk = blockIdx.x;

    unsigned mk[4];
    mk[0] = mask[0]; mk[1] = mask[1]; mk[2] = mask[2]; mk[3] = mask[3];

    // zero-fill sA (dead cols / pad must be valid zeros for MFMA)
    {
        int4 z; z.x = 0; z.y = 0; z.z = 0; z.w = 0;
        int4* p = (int4*)sA;
        #pragma unroll
        for (int i = 0; i < 4; ++i) p[tid + i * 256] = z;
    }
    __syncthreads();

    // ---------------- Phase E: encode 64 points into sA (live cols only) -----
    {
        const int m = tid >> 2;          // local point 0..63
        const int g = tid & 3;           // 4 workers per point
        int pt = blk * 64 + m;
        if (pt > npts - 1) pt = npts - 1;
        float xv[3];
        xv[0] = x[pt * 3 + 0];
        xv[1] = x[pt * 3 + 1];
        xv[2] = x[pt * 3 + 2];

        if (g == 0) {                    // raw coords, cols 0..2
            #pragma unroll
            for (int d = 0; d < 3; ++d) sA[swz(m, d, 128)] = f2bf(xv[d]);
        }
        // positional embed: sin cols 3+3f+d, cos cols 30+3f+d, freqs f = g, g+4, g+8
        for (int f = g; f < 9; f += 4) {
            float fs = (float)(1 << f);
            #pragma unroll
            for (int d = 0; d < 3; ++d) {
                bool ns = bit(mk, 3 + f * 3 + d);
                bool nc = bit(mk, 30 + f * 3 + d);
                if (ns | nc) {
                    float v = xv[d] * fs;
                    if (ns) sA[swz(m, 3 + f * 3 + d, 128)]  = f2bf(__builtin_sinf(v));
                    if (nc) sA[swz(m, 30 + f * 3 + d, 128)] = f2bf(__builtin_cosf(v));
                }
            }
        }
        // hash-grid levels g*4 .. g*4+3 -> cols 57 + 4*lvl (skipped when dead)
        #pragma unroll
        for (int li = 0; li < 4; ++li) {
            int i0 = R.r[li], i1 = R.r[4 + li], i2 = R.r[8 + li], i3 = R.r[12 + li];
            int res = (g == 0) ? i0 : (g == 1) ? i1 : (g == 2) ? i2 : i3;
            int lvl = g * 4 + li;
            int kb = 57 + lvl * 4;
            bool need = bit(mk, kb) | bit(mk, kb + 1) | bit(mk, kb + 2) | bit(mk, kb + 3);
            if (!need) continue;
            int rp1 = res + 1;
            bool dense = (rp1 <= 80);    // (res+1)^3 <= 2^19  <=>  res+1 <= 80
            float fx[3]; int pi[3];
            #pragma unroll
            for (int d = 0; d < 3; ++d) {
                float p  = xv[d] * (float)res;
                float pf = floorf(p);
                fx[d] = p - pf;
                int q = (int)pf;
                pi[d] = min(max(q, 0), res - 1);
            }
            float a0 = 0.f, a1 = 0.f, a2 = 0.f, a3 = 0.f;
            const float* tb = table + (size_t)lvl * (TSIZE * 4);
            #pragma unroll
            for (int c = 0; c < 8; ++c) {
                int cx = pi[0] + (c & 1);
                int cy = pi[1] + ((c >> 1) & 1);
                int cz = pi[2] + ((c >> 2) & 1);
                unsigned di = (unsigned)(cx + cy * rp1 + cz * rp1 * rp1);
                unsigned hi = ((unsigned)cx ^ ((unsigned)cy * 2654435761u)
                                            ^ ((unsigned)cz * 805459861u)) & (unsigned)(TSIZE - 1);
                unsigned idx = dense ? di : hi;
                float4 t = *(const float4*)(tb + (size_t)idx * 4);
                float w = ((c & 1) ? fx[0] : 1.0f - fx[0])
                        * ((c & 2) ? fx[1] : 1.0f - fx[1])
                        * ((c & 4) ? fx[2] : 1.0f - fx[2]);
                a0 += w * t.x; a1 += w * t.y; a2 += w * t.z; a3 += w * t.w;
            }
            sA[swz(m, kb + 0, 128)] = f2bf(a0);
            sA[swz(m, kb + 1, 128)] = f2bf(a1);
            sA[swz(m, kb + 2, 128)] = f2bf(a2);
            sA[swz(m, kb + 3, 128)] = f2bf(a3);
        }
    }

    // ---------------- MFMA MLP ----------------------------------------------
    const int lane = tid & 63, w = tid >> 6;       // wave w covers cols w*64..w*64+63
    const int quad = lane >> 4, l15 = lane & 15;
    const int nb = w * 64;

    float b0r[4], b1r[4], w2r[4];
    #pragma unroll
    for (int ni = 0; ni < 4; ++ni) {
        int col = nb + ni * 16 + l15;
        b0r[ni] = b0[col]; b1r[ni] = b1[col]; w2r[ni] = W2[col];
    }

    // K-tile liveness for GEMM0: skip tiles whose 32 input cols are all dead
    bool ktl[4];
    ktl[0] = mk[0] != 0u;
    ktl[1] = mk[1] != 0u;
    ktl[2] = mk[2] != 0u;
    ktl[3] = (mk[3] & 0x01FFFFFFu) != 0u;   // cols 96..120

    __syncthreads();   // sA ready

    const f32x4 zero = {0.f, 0.f, 0.f, 0.f};
    f32x4 acc[4][4];
    #pragma unroll
    for (int mi = 0; mi < 4; ++mi)
        #pragma unroll
        for (int ni = 0; ni < 4; ++ni) acc[mi][ni] = zero;

    // GEMM0: [64 x 121(pad 128)] @ W0^T -> softplus -> sB
    #pragma unroll
    for (int kt = 0; kt < 4; ++kt) {
        if (!ktl[kt]) continue;
        bf16x8 a[4], bfr[4];
        #pragma unroll
        for (int mi = 0; mi < 4; ++mi) {
            int mm = mi * 16 + l15;
            int blkk = kt * 4 + quad;
            a[mi] = *(const bf16x8*)&sA[mm * 128 + ((blkk ^ (mm & 7)) << 3)];
        }
        #pragma unroll
        for (int ni = 0; ni < 4; ++ni)
            bfr[ni] = *(const bf16x8*)&B0p[((kt * 256 + nb + ni * 16 + l15) * 4 + quad) * 8];
        #pragma unroll
        for (int mi = 0; mi < 4; ++mi)
            #pragma unroll
            for (int ni = 0; ni < 4; ++ni)
                acc[mi][ni] = __builtin_amdgcn_mfma_f32_16x16x32_bf16(a[mi], bfr[ni], acc[mi][ni], 0, 0, 0);
    }

    // epilogue0: bias + softplus -> bf16 sB (swizzled). C frag: col=lane&15, row=quad*4+r
    #pragma unroll
    for (int mi = 0; mi < 4; ++mi)
        #pragma unroll
        for (int ni = 0; ni < 4; ++ni)
            #pragma unroll
            for (int r = 0; r < 4; ++r) {
                int row = mi * 16 + quad * 4 + r;
                int col = nb + ni * 16 + l15;
                sB[swz(row, col, 256)] = f2bf(sp100(acc[mi][ni][r] + b0r[ni]));
            }

    __syncthreads();   // sB (H0) ready

    #pragma unroll
    for (int mi = 0; mi < 4; ++mi)
        #pragma unroll
        for (int ni = 0; ni < 4; ++ni) acc[mi][ni] = zero;

    // GEMM1: [64 x 256] @ W1^T
    #pragma unroll
    for (int kt = 0; kt < 8; ++kt) {
        bf16x8 a[4], bfr[4];
        #pragma unroll
        for (int mi = 0; mi < 4; ++mi) {
            int mm = mi * 16 + l15;
            int blkk = kt * 4 + quad;
            a[mi] = *(const bf16x8*)&sB[mm * 256 + ((blkk ^ (mm & 7)) << 3)];
        }
        #pragma unroll
        for (int ni = 0; ni < 4; ++ni)
            bfr[ni] = *(const bf16x8*)&B1p[((kt * 256 + nb + ni * 16 + l15) * 4 + quad) * 8];
        #pragma unroll
        for (int mi = 0; mi < 4; ++mi)
            #pragma unroll
            for (int ni = 0; ni < 4; ++ni)
                acc[mi][ni] = __builtin_amdgcn_mfma_f32_16x16x32_bf16(a[mi], bfr[ni], acc[mi][ni], 0, 0, 0);
    }

    // epilogue1 fused with layer 2: out = softplus(H0@W1^T + b1) . W2 + b2
    #pragma unroll
    for (int mi = 0; mi < 4; ++mi)
        #pragma unroll
        for (int r = 0; r < 4; ++r) {
            float p = 0.0f;
            #pragma unroll
            for (int ni = 0; ni < 4; ++ni)
                p += sp100(acc[mi][ni][r] + b1r[ni]) * w2r[ni];
            // reduce across the 16 lanes of this quad (they hold the 16 cols)
            p += __shfl_xor(p, 1);
            p += __shfl_xor(p, 2);
            p += __shfl_xor(p, 4);
            p += __shfl_xor(p, 8);
            if (l15 == 0) sP[(mi * 16 + quad * 4 + r) * 4 + w] = p;
        }

    __syncthreads();

    if (tid < 64) {
        float s = sP[tid * 4 + 0] + sP[tid * 4 + 1] + sP[tid * 4 + 2] + sP[tid * 4 + 3] + b2[0];
        int pt = blk * 64 + tid;
        if (pt < npts) out[pt] = s;
    }
}

extern "C" void kernel_launch(void* const* d_in, const int* in_sizes, int n_in,
                              void* d_out, int out_size, void* d_ws, size_t ws_size,
                              hipStream_t stream) {
    const float* x     = (const float*)d_in[0];
    const float* table = (const float*)d_in[1];
    const float* W0    = (const float*)d_in[2];
    const float* b0    = (const float*)d_in[3];
    const float* W1    = (const float*)d_in[4];
    const float* b1    = (const float*)d_in[5];
    const float* W2    = (const float*)d_in[6];
    const float* b2    = (const float*)d_in[7];
    float* out = (float*)d_out;
    int npts = in_sizes[0] / 3;

    // ws layout: B0p 32768 bf16 (64 KB) | B1p 65536 bf16 (128 KB) | mask 4 u32
    short* B0p = (short*)d_ws;
    short* B1p = B0p + 32768;
    unsigned* mask = (unsigned*)(B1p + 65536);

    // RES table: must match Python bit-for-bit -> identical libm expression.
    Res16 R;
    double s = ::pow(2.0, ::log2(2048.0 / 16.0) / 15.0);
    for (int l = 0; l < 16; ++l) R.r[l] = (int)::ceil(16.0 * ::pow(s, (double)l));

    hipLaunchKernelGGL(pack_weights, dim3(256), dim3(256), 0, stream, W0, W1, B0p, B1p, mask);
    int nblk = (npts + 63) / 64;
    hipLaunchKernelGGL(fused_mlp, dim3(nblk), dim3(256), 0, stream,
                       x, table, b0, b1, W2, b2, B0p, B1p, mask, out, npts, R);
}

// Round 3
// 424.810 us; speedup vs baseline: 1.8208x; 1.1677x over previous
//
#include <hip/hip_runtime.h>
#include <cmath>

#define TSIZE (1 << 19)   // hash table entries per level

typedef __bf16 bf16x8 __attribute__((ext_vector_type(8)));
typedef float  f32x4  __attribute__((ext_vector_type(4)));

struct Res16 { int r[16]; };

// float -> bf16 bits, round-to-nearest-even
static __device__ __forceinline__ short f2bf(float f) {
    union { float f; unsigned u; } v; v.f = f;
    unsigned r = v.u + 0x7FFFu + ((v.u >> 16) & 1u);
    return (short)(r >> 16);
}

// softplus(t) = max(t,0) + log1p(exp(-|t|))  (scale 100/0.01 folded by caller)
static __device__ __forceinline__ float spr(float t) {
    float e = __expf(-fabsf(t));
    return fmaxf(t, 0.0f) + __logf(1.0f + e);
}

// swizzled LDS offset: row m, col k, row stride `stride` (shorts).
static __device__ __forceinline__ int swz(int m, int k, int stride) {
    return m * stride + ((((k >> 3) ^ (m & 7)) << 3) | (k & 7));
}

static __device__ __forceinline__ bool bit(const unsigned mk[4], int k) {
    return (mk[k >> 5] >> (k & 31)) & 1u;
}

// Pack W0 [256,121] (x100, fold softplus beta) and W1 [256,256] into MFMA
// fragment order: ((kt*256 + n)*4 + q)*8 + j  holds  W[n][kt*32+q*8+j] (bf16).
// Block 0 additionally builds the live-input-column bitmask of W0 (parallel,
// coalesced scan + LDS atomicOr — the round-2 serial scan cost ~60 us).
__global__ __launch_bounds__(256) void pack_weights(
    const float* __restrict__ W0, const float* __restrict__ W1,
    short* __restrict__ B0p, short* __restrict__ B1p, unsigned* __restrict__ mask) {
    int tid = threadIdx.x;
    int i = blockIdx.x * 256 + tid;              // 0..65535
    int j = i & 7, q = (i >> 3) & 3, n = (i >> 5) & 255, kt = i >> 13;
    int k = kt * 32 + q * 8 + j;
    if (i < 32768) {                             // B0p: kt 0..3 (K=128, 121 used)
        B0p[i] = f2bf(k < 121 ? 100.0f * W0[n * 121 + k] : 0.0f);
    }
    B1p[i] = f2bf(W1[n * 256 + k]);              // B1p: kt 0..7 (K=256)

    if (blockIdx.x == 0) {
        __shared__ unsigned lm[4];
        if (tid < 4) lm[tid] = 0u;
        __syncthreads();
        unsigned acc[4] = {0u, 0u, 0u, 0u};
        for (int e = tid; e < 256 * 121; e += 256) {   // coalesced flat scan
            if (W0[e] != 0.0f) { int kc = e % 121; acc[kc >> 5] |= 1u << (kc & 31); }
        }
        #pragma unroll
        for (int wi = 0; wi < 4; ++wi) if (acc[wi]) atomicOr(&lm[wi], acc[wi]);
        __syncthreads();
        if (tid < 4) mask[tid] = lm[tid];
    }
}

// Fused encode + 3-layer MLP. Both GEMMs computed transposed (A = weights,
// B = points^T): C-frag then holds 4 consecutive hidden units per lane ->
// packed ds_write_b64 H0 stores, and layer-2 reduce needs only 2 shuffles.
__global__ __launch_bounds__(256, 4) void fused_mlp(
    const float* __restrict__ x, const float* __restrict__ table,
    const float* __restrict__ b0, const float* __restrict__ b1,
    const float* __restrict__ W2, const float* __restrict__ b2,
    const short* __restrict__ B0p, const short* __restrict__ B1p,
    const unsigned* __restrict__ mask,
    float* __restrict__ out, int npts, Res16 R)
{
    __shared__ short sB[64 * 256];   // 32 KB; first 16 KB aliased as sA [64][128]
    __shared__ float sX[192];        // staged x for 64 points
    __shared__ float sC[768];        // 100*b0 | 100*b1 | 0.01*W2
    __shared__ float sP[256];        // layer-2 partials [point][wave]

    short* sA = sB;                  // union: sA dead before sB is written
    const int tid = threadIdx.x;
    const int blk = blockIdx.x;

    unsigned mk[4];
    mk[0] = mask[0]; mk[1] = mask[1]; mk[2] = mask[2]; mk[3] = mask[3];

    // ---- stage constants + x, zero-fill sA (dead cols must be 0) ----------
    {
        sC[tid]       = 100.0f * b0[tid];
        sC[256 + tid] = 100.0f * b1[tid];
        sC[512 + tid] = 0.01f  * W2[tid];
        if (tid < 192) {
            int xi = blk * 192 + tid;
            sX[tid] = (xi < npts * 3) ? x[xi] : 0.0f;
        }
        int4 z; z.x = 0; z.y = 0; z.z = 0; z.w = 0;
        int4* p = (int4*)sA;
        #pragma unroll
        for (int i = 0; i < 4; ++i) p[tid + i * 256] = z;
    }
    __syncthreads();

    // ---- Phase E: encode live input cols of the 64 points into sA ---------
    {
        const int m = tid >> 2;          // local point 0..63
        const int g = tid & 3;           // 4 workers per point
        float xv[3];
        xv[0] = sX[m * 3 + 0]; xv[1] = sX[m * 3 + 1]; xv[2] = sX[m * 3 + 2];

        if (g == 0) {                    // raw coords, cols 0..2
            #pragma unroll
            for (int d = 0; d < 3; ++d) sA[swz(m, d, 128)] = f2bf(xv[d]);
        }
        // positional embed: sin cols 3+3f+d, cos cols 30+3f+d
        for (int f = g; f < 9; f += 4) {
            float fs = (float)(1 << f);
            #pragma unroll
            for (int d = 0; d < 3; ++d) {
                bool ns = bit(mk, 3 + f * 3 + d);
                bool nc = bit(mk, 30 + f * 3 + d);
                if (ns | nc) {
                    float v = xv[d] * fs;
                    if (ns) sA[swz(m, 3 + f * 3 + d, 128)]  = f2bf(__builtin_sinf(v));
                    if (nc) sA[swz(m, 30 + f * 3 + d, 128)] = f2bf(__builtin_cosf(v));
                }
            }
        }
        // hash-grid levels g*4..g*4+3 -> cols 57 + 4*lvl (skipped when dead)
        #pragma unroll
        for (int li = 0; li < 4; ++li) {
            int i0 = R.r[li], i1 = R.r[4 + li], i2 = R.r[8 + li], i3 = R.r[12 + li];
            int res = (g == 0) ? i0 : (g == 1) ? i1 : (g == 2) ? i2 : i3;
            int lvl = g * 4 + li;
            int kb = 57 + lvl * 4;
            bool need = bit(mk, kb) | bit(mk, kb + 1) | bit(mk, kb + 2) | bit(mk, kb + 3);
            if (!need) continue;
            int rp1 = res + 1;
            bool dense = (rp1 <= 80);    // (res+1)^3 <= 2^19
            float fx[3]; int pi[3];
            #pragma unroll
            for (int d = 0; d < 3; ++d) {
                float p  = xv[d] * (float)res;
                float pf = floorf(p);
                fx[d] = p - pf;
                int qv = (int)pf;
                pi[d] = min(max(qv, 0), res - 1);
            }
            float a0 = 0.f, a1 = 0.f, a2 = 0.f, a3 = 0.f;
            const float* tb = table + (size_t)lvl * (TSIZE * 4);
            #pragma unroll
            for (int c = 0; c < 8; ++c) {
                int cx = pi[0] + (c & 1);
                int cy = pi[1] + ((c >> 1) & 1);
                int cz = pi[2] + ((c >> 2) & 1);
                unsigned di = (unsigned)(cx + cy * rp1 + cz * rp1 * rp1);
                unsigned hi = ((unsigned)cx ^ ((unsigned)cy * 2654435761u)
                                            ^ ((unsigned)cz * 805459861u)) & (unsigned)(TSIZE - 1);
                unsigned idx = dense ? di : hi;
                float4 t = *(const float4*)(tb + (size_t)idx * 4);
                float wgt = ((c & 1) ? fx[0] : 1.0f - fx[0])
                          * ((c & 2) ? fx[1] : 1.0f - fx[1])
                          * ((c & 4) ? fx[2] : 1.0f - fx[2]);
                a0 += wgt * t.x; a1 += wgt * t.y; a2 += wgt * t.z; a3 += wgt * t.w;
            }
            sA[swz(m, kb + 0, 128)] = f2bf(a0);
            sA[swz(m, kb + 1, 128)] = f2bf(a1);
            sA[swz(m, kb + 2, 128)] = f2bf(a2);
            sA[swz(m, kb + 3, 128)] = f2bf(a3);
        }
    }

    const int lane = tid & 63, w = tid >> 6;    // wave w: hidden cols nb..nb+63
    const int quad = lane >> 4, l15 = lane & 15;
    const int nb = w * 64;

    bool ktl[4];
    ktl[0] = mk[0] != 0u;
    ktl[1] = mk[1] != 0u;
    ktl[2] = mk[2] != 0u;
    ktl[3] = (mk[3] & 0x01FFFFFFu) != 0u;

    __syncthreads();   // sA ready

    const f32x4 zero = {0.f, 0.f, 0.f, 0.f};
    f32x4 acc[4][4];   // [ni (hidden frag)][mj (point frag)]
    #pragma unroll
    for (int ni = 0; ni < 4; ++ni)
        #pragma unroll
        for (int mj = 0; mj < 4; ++mj) acc[ni][mj] = zero;

    // GEMM0': D[n][m] = sum_k W0'[n][k] X[m][k]
    #pragma unroll
    for (int kt = 0; kt < 4; ++kt) {
        if (!ktl[kt]) continue;
        bf16x8 afr[4], bfr[4];
        #pragma unroll
        for (int ni = 0; ni < 4; ++ni)
            afr[ni] = *(const bf16x8*)&B0p[((kt * 256 + nb + ni * 16 + l15) * 4 + quad) * 8];
        #pragma unroll
        for (int mj = 0; mj < 4; ++mj) {
            int m = mj * 16 + l15, c = kt * 4 + quad;
            bfr[mj] = *(const bf16x8*)&sA[m * 128 + ((c ^ (m & 7)) << 3)];
        }
        #pragma unroll
        for (int ni = 0; ni < 4; ++ni)
            #pragma unroll
            for (int mj = 0; mj < 4; ++mj)
                acc[ni][mj] = __builtin_amdgcn_mfma_f32_16x16x32_bf16(afr[ni], bfr[mj], acc[ni][mj], 0, 0, 0);
    }

    __syncthreads();   // all sA reads done before epilogue overwrites the union

    // epilogue0: H0' = softplus(acc + 100*b0), packed b64 stores (4 consecutive n)
    #pragma unroll
    for (int ni = 0; ni < 4; ++ni) {
        float4 b0v = *(const float4*)&sC[nb + ni * 16 + quad * 4];
        int c = (nb + ni * 16 + quad * 4) >> 3;
        #pragma unroll
        for (int mj = 0; mj < 4; ++mj) {
            int m = mj * 16 + l15;
            short4 h;
            h.x = f2bf(spr(acc[ni][mj][0] + b0v.x));
            h.y = f2bf(spr(acc[ni][mj][1] + b0v.y));
            h.z = f2bf(spr(acc[ni][mj][2] + b0v.z));
            h.w = f2bf(spr(acc[ni][mj][3] + b0v.w));
            *(short4*)&sB[m * 256 + (((c ^ (m & 7)) << 3) | ((quad & 1) << 2))] = h;
        }
    }

    __syncthreads();   // sB (H0') ready

    #pragma unroll
    for (int ni = 0; ni < 4; ++ni)
        #pragma unroll
        for (int mj = 0; mj < 4; ++mj) acc[ni][mj] = zero;

    // GEMM1': D[n][m] = sum_k W1[n][k] H0'[m][k]   (K = 256)
    #pragma unroll
    for (int kt = 0; kt < 8; ++kt) {
        bf16x8 afr[4], bfr[4];
        #pragma unroll
        for (int ni = 0; ni < 4; ++ni)
            afr[ni] = *(const bf16x8*)&B1p[((kt * 256 + nb + ni * 16 + l15) * 4 + quad) * 8];
        #pragma unroll
        for (int mj = 0; mj < 4; ++mj) {
            int m = mj * 16 + l15, c = kt * 4 + quad;
            bfr[mj] = *(const bf16x8*)&sB[m * 256 + ((c ^ (m & 7)) << 3)];
        }
        #pragma unroll
        for (int ni = 0; ni < 4; ++ni)
            #pragma unroll
            for (int mj = 0; mj < 4; ++mj)
                acc[ni][mj] = __builtin_amdgcn_mfma_f32_16x16x32_bf16(afr[ni], bfr[mj], acc[ni][mj], 0, 0, 0);
    }

    // epilogue1 fused with layer 2: out = softplus(.)*0.01W2 summed over n
    #pragma unroll
    for (int mj = 0; mj < 4; ++mj) {
        float p = 0.0f;
        #pragma unroll
        for (int ni = 0; ni < 4; ++ni) {
            float4 b1v = *(const float4*)&sC[256 + nb + ni * 16 + quad * 4];
            float4 w2v = *(const float4*)&sC[512 + nb + ni * 16 + quad * 4];
            p += spr(acc[ni][mj][0] + b1v.x) * w2v.x;
            p += spr(acc[ni][mj][1] + b1v.y) * w2v.y;
            p += spr(acc[ni][mj][2] + b1v.z) * w2v.z;
            p += spr(acc[ni][mj][3] + b1v.w) * w2v.w;
        }
        p += __shfl_xor(p, 16);   // sum over quads (same l15)
        p += __shfl_xor(p, 32);
        if (quad == 0) sP[(mj * 16 + l15) * 4 + w] = p;
    }

    __syncthreads();

    if (tid < 64) {
        float s = sP[tid * 4 + 0] + sP[tid * 4 + 1] + sP[tid * 4 + 2] + sP[tid * 4 + 3] + b2[0];
        int pt = blk * 64 + tid;
        if (pt < npts) out[pt] = s;
    }
}

extern "C" void kernel_launch(void* const* d_in, const int* in_sizes, int n_in,
                              void* d_out, int out_size, void* d_ws, size_t ws_size,
                              hipStream_t stream) {
    const float* x     = (const float*)d_in[0];
    const float* table = (const float*)d_in[1];
    const float* W0    = (const float*)d_in[2];
    const float* b0    = (const float*)d_in[3];
    const float* W1    = (const float*)d_in[4];
    const float* b1    = (const float*)d_in[5];
    const float* W2    = (const float*)d_in[6];
    const float* b2    = (const float*)d_in[7];
    float* out = (float*)d_out;
    int npts = in_sizes[0] / 3;

    // ws layout: B0p 32768 bf16 | B1p 65536 bf16 | mask 4 u32
    short* B0p = (short*)d_ws;
    short* B1p = B0p + 32768;
    unsigned* mask = (unsigned*)(B1p + 65536);

    // RES table: must match Python bit-for-bit -> identical libm expression.
    Res16 R;
    double s = ::pow(2.0, ::log2(2048.0 / 16.0) / 15.0);
    for (int l = 0; l < 16; ++l) R.r[l] = (int)::ceil(16.0 * ::pow(s, (double)l));

    hipLaunchKernelGGL(pack_weights, dim3(256), dim3(256), 0, stream, W0, W1, B0p, B1p, mask);
    int nblk = (npts + 63) / 64;
    hipLaunchKernelGGL(fused_mlp, dim3(nblk), dim3(256), 0, stream,
                       x, table, b0, b1, W2, b2, B0p, B1p, mask, out, npts, R);
}